// Round 8
// baseline (39107.770 us; speedup 1.0000x reference)
//
#include <hip/hip_runtime.h>
#include <math.h>

// QPLayer: batched primal-dual IPM, Q=0, G=-I. Full 104x104 augmented KKT
// [[diag(w),A^T],[A,0]] solved per iteration with partially-pivoted LU
// (getrf-style, row-owner elimination), faithful to jnp.linalg.solve.
// ROUND 8 KEY FIX: the harness has no float64 buffer path (dtype map:
// bf16/f32/i32 only) -> float64 inputs are DELIVERED AS FLOAT32. Rounds 2-6
// read f64 from the f32 buffer (glued garbage doubles -> consistent wrong
// optimum 57.25); round 7 read bf16 (NaN patterns). Read A/log_z0/u as f32,
// upcast to f64. Robustness: in-kernel discriminator (A ~ U(0,1): all f32
// values in [0,1] <=> f32 delivery) falls back to f64 reads if ever needed.
// One block (256 threads) per batch element; KKT in LDS (column-major ld=104).

#define NXV   64
#define MEQ   40
#define NK    104            // 64 + 40
#define NITER 25
#define SIGMA_C 0.1
#define FTB_C   0.99
#define SA    65             // LDS row stride for A (doubles)
#define MINPIV 1e-250

__global__ __launch_bounds__(256)
void qp_ipm_kernel(const float* __restrict__ puzzles,
                   const void* __restrict__ Araw,
                   const void* __restrict__ lzraw,
                   const void* __restrict__ uraw,
                   float* __restrict__ out)
{
    __shared__ double K[NK * NK];     // column-major, ld = NK (86,528 B)
    __shared__ double Ald[MEQ * SA];  // A row-major padded (20,800 B)
    __shared__ double rhs[NK], acc[NK], sol[NK];
    __shared__ double xv[NXV], sv[NXV], zv[NXV], rsv[NXV], rcv[NXV], wv[NXV], tv[NXV];
    __shared__ double yv[MEQ], bv[MEQ];
    __shared__ double alphaS;
    __shared__ int    pS, f32flag;

    const int tid = threadIdx.x;
    const int b   = blockIdx.x;

    // ---- input-encoding discriminator: A ~ U(0,1) elementwise iff f32 view ----
    if (tid == 0) f32flag = 1;
    __syncthreads();
    {
        const float* Af = (const float*)Araw;
        for (int e = tid; e < MEQ * NXV; e += 256) {
            const float v = Af[e];
            if (!(v >= 0.0f && v <= 1.0f)) f32flag = 0;   // benign race: all write 0
        }
    }
    __syncthreads();
    const int isF32 = f32flag;

    // ---- setup: stage A -> f64 LDS ----
    for (int e = tid; e < MEQ * NXV; e += 256) {
        int r = e >> 6, c = e & 63;
        Ald[r * SA + c] = isF32 ? (double)((const float*)Araw)[e]
                                : ((const double*)Araw)[e];
    }
    if (tid < NXV) {
        const double lz = isF32 ? (double)((const float*)lzraw)[tid]
                                : ((const double*)lzraw)[tid];
        tv[tid] = exp(lz);
        xv[tid] = 0.0; sv[tid] = 1.0; zv[tid] = 1.0;
    } else if (tid - 64 < MEQ) {
        yv[tid - 64] = 0.0;
    }
    __syncthreads();
    if (tid >= 64 && tid - 64 < MEQ) {          // b = A @ exp(log_z0)
        int j = tid - 64; double a = 0.0;
        for (int i = 0; i < NXV; ++i) a += Ald[j * SA + i] * tv[i];
        bv[j] = a;
    }
    __syncthreads();

    const double u_i = (tid < NXV)
        ? (isF32 ? (double)((const float*)uraw)[tid] : ((const double*)uraw)[tid])
        : 0.0;
    const double p_i = (tid < NXV) ? -(double)puzzles[b * NXV + tid] : 0.0;

    for (int it = 0; it < NITER; ++it) {
        // ---- P1: residuals, w, rhs ----
        if (tid < NXV) {
            const int i = tid;
            double aty = 0.0;
            for (int j = 0; j < MEQ; ++j) aty += Ald[j * SA + i] * yv[j];
            const double zi = zv[i], si = sv[i];
            const double rd = p_i + aty - zi;          // Q=0, G^T z = -z
            const double rs = si - xv[i] - u_i;        // -x + s - u
            rsv[i] = rs;
            double m = si * zi;
            for (int off = 32; off; off >>= 1) m += __shfl_xor(m, off, 64);
            const double mu = m * (1.0 / 64.0);
            const double rc = (SIGMA_C * mu - zi * si + zi * rs) / si;
            rcv[i] = rc;
            rhs[i] = rc - rd;                          // rhs_x
            wv[i]  = zi / si;
        } else if (tid - 64 < MEQ) {
            const int j = tid - 64; double a = 0.0;
            for (int i = 0; i < NXV; ++i) a += Ald[j * SA + i] * xv[i];
            rhs[64 + j] = -(a - bv[j]);                // -rp
        } else if (tid >= 128 && tid - 128 < NK) {
            acc[tid - 128] = 0.0;
        }
        __syncthreads();

        // ---- P2: assemble KKT (column-major) ----
        for (int e = tid; e < NK * NK; e += 256) {
            const int c = e / NK, r = e - c * NK;
            double v;
            if (r < NXV) {
                v = (c < NXV) ? ((r == c) ? wv[r] : 0.0)
                              : Ald[(c - NXV) * SA + r];      // A^T block
            } else {
                v = (c < NXV) ? Ald[(r - NXV) * SA + c] : 0.0; // A block
            }
            K[e] = v;
        }
        __syncthreads();

        // ---- P3: LU with partial pivoting, row-owner updates, pivot floor ----
        for (int k = 0; k < NK; ++k) {
            // (a) pivot = argmax |K[i,k]|, i>=k, first index on ties (wave 0)
            if (tid < 64) {
                const int i1 = k + tid, i2 = k + 64 + tid;
                double v1 = (i1 < NK) ? fabs(K[i1 + k * NK]) : -1.0;
                double v2 = (i2 < NK) ? fabs(K[i2 + k * NK]) : -1.0;
                double v; int idx;
                if (v2 > v1) { v = v2; idx = i2; } else { v = v1; idx = i1; }
                for (int off = 32; off; off >>= 1) {
                    double ov = __shfl_xor(v, off, 64);
                    int    oi = __shfl_xor(idx, off, 64);
                    if (ov > v || (ov == v && oi < idx)) { v = ov; idx = oi; }
                }
                if (tid == 0) pS = idx;
            }
            __syncthreads();
            // (b) swap rows k <-> p (all columns, LAPACK-style) + rhs
            const int p = pS;
            if (p != k) {
                if (tid < NK) {
                    double t = K[k + tid * NK];
                    K[k + tid * NK] = K[p + tid * NK];
                    K[p + tid * NK] = t;
                } else if (tid == NK) {
                    double t = rhs[k]; rhs[k] = rhs[p]; rhs[p] = t;
                }
            }
            __syncthreads();
            // (c) eliminate: thread tid owns row tid; fused forward-sub on rhs
            double piv = K[k + k * NK];
            piv = (fabs(piv) >= MINPIV) ? piv : copysign(MINPIV, piv);
            if (tid > k && tid < NK) {
                const double lc = K[tid + k * NK] / piv;
                K[tid + k * NK] = lc;
                rhs[tid] -= lc * rhs[k];
                for (int j = k + 1; j < NK; ++j)
                    K[tid + j * NK] -= lc * K[k + j * NK];
            }
            __syncthreads();
        }

        // ---- P4: back-substitution (U sol = rhs), floored diagonal ----
        for (int k = NK - 1; k >= 0; --k) {
            double dk = K[k + k * NK];
            dk = (fabs(dk) >= MINPIV) ? dk : copysign(MINPIV, dk);
            const double val = (rhs[k] - acc[k]) / dk;
            if (tid == k) sol[k] = val;
            if (tid < k) acc[tid] += K[tid + k * NK] * val;
            __syncthreads();
        }

        // ---- P5: step length + updates ----
        if (tid < NXV) {
            const int i = tid;
            const double dx = sol[i];
            const double ds = dx - rsv[i];             // -rs + dx
            const double dz = rcv[i] - wv[i] * dx;     // rc - w*dx
            double r = 1e300;
            if (ds < 0.0) r = -sv[i] / ds;
            if (dz < 0.0) r = fmin(r, -zv[i] / dz);
            for (int off = 32; off; off >>= 1) r = fmin(r, __shfl_xor(r, off, 64));
            const double alpha = fmin(1.0, FTB_C * r);
            xv[i] += alpha * dx;
            sv[i] += alpha * ds;
            zv[i] += alpha * dz;
            if (tid == 0) alphaS = alpha;
        }
        __syncthreads();
        if (tid >= 64 && tid - 64 < MEQ) {
            const int j = tid - 64;
            yv[j] += alphaS * sol[64 + j];
        }
        __syncthreads();
    }

    if (tid < NXV) out[b * NXV + tid] = (float)xv[tid];
}

extern "C" void kernel_launch(void* const* d_in, const int* in_sizes, int n_in,
                              void* d_out, int out_size, void* d_ws, size_t ws_size,
                              hipStream_t stream) {
    const float* puzzles = (const float*)d_in[0];
    const void*  A       = d_in[1];
    const void*  logz0   = d_in[2];
    // d_in[3] = Q (zeros, structural), d_in[4] = G (-I, structural)
    const void*  u       = d_in[5];
    float* out = (float*)d_out;

    const int n_batch = in_sizes[0] / NXV;   // 1024
    qp_ipm_kernel<<<n_batch, 256, 0, stream>>>(puzzles, A, logz0, u, out);
}

// Round 9
// 2533.308 us; speedup vs baseline: 15.4374x; 15.4374x over previous
//
#include <hip/hip_runtime.h>
#include <math.h>

// QPLayer: batched primal-dual IPM, Q=0, G=-I (LP). Inputs declared f64 are
// DELIVERED AS F32 by the harness (established round 8). Schur-complement
// formulation: S = A diag(s/z) A^T (40x40 SPD), complete-diagonal-pivoted
// LDL^T with relative pivot-drop (piv <= maxd*1e-12 -> 1e300, PCx-style).
// Validated: Schur and full-KKT LU agreed bit-exactly in fp32 on the
// (garbage-input) round-2/5 A/B; threshold margin 36x vs round-8 absmax.
// ONE WAVE (64 threads) per batch element: all reductions are register
// butterflies; single-wave workgroup => barriers are just lgkmcnt drains.
// State x,s,z,rs,rc,d,tv in registers; only cross-lane arrays in LDS (~37KB
// -> 4 blocks/CU; grid 1024 = 256 CU x 4, fully resident in one dispatch).

#define NXV   64
#define MEQ   40
#define NITER 25
#define SIGMA_C 0.1
#define FTB_C   0.99
#define SA 65    // LDS row stride for A (doubles)
#define SS 41    // LDS row stride for S (doubles)
#define PIV_DROP_REL 1e-12

__global__ __launch_bounds__(64)
void qp_ipm_kernel(const float* __restrict__ puzzles,
                   const float* __restrict__ Af,
                   const float* __restrict__ lzf,
                   const float* __restrict__ uf,
                   float* __restrict__ out)
{
    __shared__ double Ald[MEQ * SA];                 // 20,800 B
    __shared__ double S[MEQ * SS];                   // 13,120 B
    __shared__ double dvec[NXV], txv[NXV];           //  1,024 B
    __shared__ double fy[MEQ], accv[MEQ], dyv[MEQ], bv[MEQ], Dv[MEQ], yv[MEQ]; // 1,920 B
    __shared__ int    pidx[MEQ];                     //    160 B

    const int tid = threadIdx.x;   // 0..63, one wave
    const int b   = blockIdx.x;

    // ---- setup: A (f32->f64) into LDS; b = A @ exp(log_z0) ----
    for (int e = tid; e < MEQ * NXV; e += 64) {
        const int r = e >> 6, c = e & 63;
        Ald[r * SA + c] = (double)Af[e];
    }
    txv[tid] = exp((double)lzf[tid]);
    if (tid < MEQ) yv[tid] = 0.0;
    __syncthreads();
    if (tid < MEQ) {
        double a = 0.0;
        for (int i = 0; i < NXV; ++i) a += Ald[tid * SA + i] * txv[i];
        bv[tid] = a;
    }
    __syncthreads();

    const double u_i = (double)uf[tid];
    const double p_i = -(double)puzzles[b * NXV + tid];
    double x_r = 0.0, s_r = 1.0, z_r = 1.0;

    for (int it = 0; it < NITER; ++it) {
        // ---- P1a: residuals/scalings (all lanes, register state) ----
        double aty = 0.0;
        for (int j = 0; j < MEQ; ++j) aty += Ald[j * SA + tid] * yv[j];
        const double rd = p_i + aty - z_r;           // Q=0, G^T z = -z
        const double rs = s_r - x_r - u_i;           // -x + s - u
        double m = s_r * z_r;
        for (int off = 32; off; off >>= 1) m += __shfl_xor(m, off, 64);
        const double mu = m * (1.0 / 64.0);
        const double rc = (SIGMA_C * mu - z_r * s_r + z_r * rs) / s_r;
        const double rx = rc - rd;                   // rhs_x
        const double d  = s_r / z_r;
        const double tv = d * rx;
        dvec[tid] = d;
        txv[tid]  = tv + x_r;                        // for fy = A(d*rx + x) - b
        __syncthreads();

        // ---- P1b + P2: rhs_y (lanes<40) then S = A diag(d) A^T tiles (lanes<55)
        if (tid < MEQ) {
            double a = 0.0;
            for (int i = 0; i < NXV; ++i) a += Ald[tid * SA + i] * txv[i];
            fy[tid]   = a - bv[tid];                 // A(d*rx) + rp
            accv[tid] = 0.0;
            pidx[tid] = tid;
        }
        if (tid < 55) {
            int uu = tid, mb = 0;
            while (uu > mb) { uu -= (mb + 1); ++mb; }
            const int nb = uu;
            double a00=0,a01=0,a02=0,a03=0, a10=0,a11=0,a12=0,a13=0,
                   a20=0,a21=0,a22=0,a23=0, a30=0,a31=0,a32=0,a33=0;
            const double* Am = &Ald[(4 * mb) * SA];
            const double* An = &Ald[(4 * nb) * SA];
            for (int k = 0; k < NXV; ++k) {
                const double dk = dvec[k];
                const double r0 = Am[0*SA+k], r1 = Am[1*SA+k], r2 = Am[2*SA+k], r3 = Am[3*SA+k];
                const double c0 = An[0*SA+k]*dk, c1 = An[1*SA+k]*dk, c2 = An[2*SA+k]*dk, c3 = An[3*SA+k]*dk;
                a00 += r0*c0; a01 += r0*c1; a02 += r0*c2; a03 += r0*c3;
                a10 += r1*c0; a11 += r1*c1; a12 += r1*c2; a13 += r1*c3;
                a20 += r2*c0; a21 += r2*c1; a22 += r2*c2; a23 += r2*c3;
                a30 += r3*c0; a31 += r3*c1; a32 += r3*c2; a33 += r3*c3;
            }
            double* Sp = &S[(4 * mb) * SS + 4 * nb];
            Sp[0*SS+0]=a00; Sp[0*SS+1]=a01; Sp[0*SS+2]=a02; Sp[0*SS+3]=a03;
            Sp[1*SS+0]=a10; Sp[1*SS+1]=a11; Sp[1*SS+2]=a12; Sp[1*SS+3]=a13;
            Sp[2*SS+0]=a20; Sp[2*SS+1]=a21; Sp[2*SS+2]=a22; Sp[2*SS+3]=a23;
            Sp[3*SS+0]=a30; Sp[3*SS+1]=a31; Sp[3*SS+2]=a32; Sp[3*SS+3]=a33;
        }
        __syncthreads();
        // mirror lower -> upper (full symmetric storage for pivoting)
        for (int e = tid; e < MEQ * MEQ; e += 64) {
            const int i = e / MEQ, j = e - i * MEQ;
            if (i < j) S[i * SS + j] = S[j * SS + i];
        }
        __syncthreads();

        // ---- P3: complete-diagonal-pivoted LDL^T + fused forward solve ----
        double maxd = 0.0;
        for (int k = 0; k < MEQ; ++k) {
            // argmax of remaining diagonal — register butterfly, all lanes agree
            double v  = (tid >= k && tid < MEQ) ? S[tid * SS + tid] : -1.0e308;
            int   idx = tid;
            for (int off = 32; off; off >>= 1) {
                const double ov = __shfl_xor(v, off, 64);
                const int    oi = __shfl_xor(idx, off, 64);
                if (ov > v || (ov == v && oi < idx)) { v = ov; idx = oi; }
            }
            const int p = idx;
            if (p != k) {   // symmetric interchange, disjoint lane work
                if (tid < MEQ && tid != k && tid != p) {
                    double t1 = S[k*SS+tid]; S[k*SS+tid] = S[p*SS+tid]; S[p*SS+tid] = t1;
                    double t2 = S[tid*SS+k]; S[tid*SS+k] = S[tid*SS+p]; S[tid*SS+p] = t2;
                } else if (tid == k) {
                    double t = S[k*SS+k]; S[k*SS+k] = S[p*SS+p]; S[p*SS+p] = t;
                } else if (tid == p) {
                    double t = fy[k]; fy[k] = fy[p]; fy[p] = t;
                    int ti = pidx[k]; pidx[k] = pidx[p]; pidx[p] = ti;
                }
            }
            __syncthreads();
            double piv = S[k * SS + k];                 // broadcast read
            if (k == 0) maxd = piv;
            if (!(piv > maxd * PIV_DROP_REL)) piv = 1.0e300;   // drop direction
            if (tid == 0) Dv[k] = piv;
            const double invP = 1.0 / piv;
            const double g    = fy[k] * invP;
            if (tid > k && tid < MEQ) {
                const double sik = S[tid * SS + k];
                const double ci  = sik * invP;
                fy[tid] -= sik * g;
                for (int j = k + 1; j < MEQ; ++j)
                    S[tid * SS + j] -= ci * S[k * SS + j];
            }
            __syncthreads();
        }

        // ---- P4: backward solve (L^T), un-permute into dyv ----
        for (int k = MEQ - 1; k >= 0; --k) {
            const double dyk = (fy[k] - accv[k]) / Dv[k];   // broadcast reads
            if (tid == k) dyv[pidx[k]] = dyk;
            if (tid < k) accv[tid] += S[k * SS + tid] * dyk;
            __syncthreads();
        }

        // ---- P5: dx/ds/dz, ratio test (butterfly), updates ----
        double atdy = 0.0;
        for (int j = 0; j < MEQ; ++j) atdy += Ald[j * SA + tid] * dyv[j];
        const double dx = tv - d * atdy;             // d*(rx - A^T dy)
        const double ds = dx - rs;                   // -rs + dx
        const double dz = rc - (z_r / s_r) * dx;
        double r = 1.0e300;
        if (ds < 0.0) r = -s_r / ds;
        if (dz < 0.0) r = fmin(r, -z_r / dz);
        for (int off = 32; off; off >>= 1) r = fmin(r, __shfl_xor(r, off, 64));
        const double alpha = fmin(1.0, FTB_C * r);
        x_r += alpha * dx;
        s_r += alpha * ds;
        z_r += alpha * dz;
        if (tid < MEQ) yv[tid] += alpha * dyv[tid];
        __syncthreads();
    }

    out[b * NXV + tid] = (float)x_r;
}

extern "C" void kernel_launch(void* const* d_in, const int* in_sizes, int n_in,
                              void* d_out, int out_size, void* d_ws, size_t ws_size,
                              hipStream_t stream) {
    const float* puzzles = (const float*)d_in[0];
    const float* A       = (const float*)d_in[1];   // declared f64, delivered f32
    const float* logz0   = (const float*)d_in[2];
    // d_in[3] = Q (zeros, structural), d_in[4] = G (-I, structural)
    const float* u       = (const float*)d_in[5];
    float* out = (float*)d_out;

    const int n_batch = in_sizes[0] / NXV;   // 1024
    qp_ipm_kernel<<<n_batch, 64, 0, stream>>>(puzzles, A, logz0, u, out);
}

// Round 13
// 2179.247 us; speedup vs baseline: 17.9455x; 1.1625x over previous
//
#include <hip/hip_runtime.h>
#include <math.h>

// QPLayer: batched primal-dual IPM, Q=0, G=-I (LP). f64 inputs DELIVERED AS F32
// (established round 8). Schur complement S = A diag(s/z) A^T (40x40), solved
// with COMPLETE-DIAGONAL-PIVOTED LDL^T (greedy max pivot; fixed order exploded
// in round 10), fully register-resident.
// ROUND 13 FIX: rounds 10-12 called __shfl(d_r, k) INSIDE the divergent
// `if (tid < 55)` S-build branch -> reads from inactive lanes 55..63 are
// UNDEFINED -> columns 55..63 of S scaled by garbage every iteration ->
// convergence to wrong vertex on some elements (stable absmax 7.2, bit-equal
// across rounds because both converge to the same wrong fixed point).
// Fix: stage d into LDS (written by all 64 lanes, uniform flow) and read
// dl[k] inside the branch — restores round 9's exact S-build numerics.
// 3 barriers/iter. One wave (64 lanes) per batch element; 1024 waves = 4/CU
// (structural). LDS 34.4 KB; launch_bounds(64,1) -> up to 512 VGPRs, no spill.

#define NXV   64
#define MEQ   40
#define NITER 25
#define SIGMA_C 0.1
#define FTB_C   0.99
#define SA 65    // LDS row stride for A (doubles)
#define SS 41    // LDS row stride for S staging (doubles)
#define PIV_DROP_REL 1e-12

__global__ __launch_bounds__(64, 1)
void qp_ipm_kernel(const float* __restrict__ puzzles,
                   const float* __restrict__ Af,
                   const float* __restrict__ lzf,
                   const float* __restrict__ uf,
                   float* __restrict__ out)
{
    __shared__ double Ald[MEQ * SA];   // 20,800 B
    __shared__ double Sl[MEQ * SS];    // 13,120 B
    __shared__ double dl[NXV];         //    512 B  (d staging: uniform-flow write)

    const int tid = threadIdx.x;       // 0..63, one wave
    const int b   = blockIdx.x;
    const int row = (tid < MEQ) ? tid : 0;

    // ---- setup: A (f32->f64) into LDS; b_r = (A @ exp(log_z0))_row ----
    for (int e = tid; e < MEQ * NXV; e += 64)
        Ald[(e >> 6) * SA + (e & 63)] = (double)Af[e];
    const double ez = exp((double)lzf[tid]);
    __syncthreads();
    double b_r = 0.0;
    #pragma unroll 4
    for (int i = 0; i < NXV; ++i) b_r += Ald[row * SA + i] * __shfl(ez, i, 64);

    const double u_i = (double)uf[tid];
    const double p_i = -(double)puzzles[b * NXV + tid];
    double x_r = 0.0, s_r = 1.0, z_r = 1.0, y_r = 0.0;

    for (int it = 0; it < NITER; ++it) {
        // ---- P1: residuals/scalings, registers (uniform flow) ----
        double aty = 0.0;
        #pragma unroll 4
        for (int j = 0; j < MEQ; ++j) aty += Ald[j * SA + tid] * __shfl(y_r, j, 64);
        const double rd = p_i + aty - z_r;          // Q=0, G^T z = -z
        const double rs = s_r - x_r - u_i;          // -x + s - u
        double m = s_r * z_r;
        for (int off = 32; off; off >>= 1) m += __shfl_xor(m, off, 64);
        const double mu = m * (1.0 / 64.0);
        const double rc = (SIGMA_C * mu - z_r * s_r + z_r * rs) / s_r;
        const double rx = rc - rd;                  // rhs_x
        const double d_r = s_r / z_r;
        const double v_r = d_r * rx + x_r;          // fy = A v - b

        double fy_r = 0.0;                          // rhs_y at lane row
        #pragma unroll 4
        for (int i = 0; i < NXV; ++i) fy_r += Ald[row * SA + i] * __shfl(v_r, i, 64);
        fy_r -= b_r;

        dl[tid] = d_r;                              // stage d (all 64 lanes)
        __syncthreads();                            // barrier 0: dl visible

        // ---- P2: S = A diag(d) A^T, 4x4 lower tiles (lanes<55) -> LDS ----
        if (tid < 55) {
            int uu = tid, mb = 0;
            while (uu > mb) { uu -= (mb + 1); ++mb; }
            const int nb = uu;
            double a00=0,a01=0,a02=0,a03=0, a10=0,a11=0,a12=0,a13=0,
                   a20=0,a21=0,a22=0,a23=0, a30=0,a31=0,a32=0,a33=0;
            const double* Am = &Ald[(4 * mb) * SA];
            const double* An = &Ald[(4 * nb) * SA];
            for (int k = 0; k < NXV; ++k) {
                const double dk = dl[k];            // LDS read — no divergent shfl
                const double r0 = Am[0*SA+k], r1 = Am[1*SA+k], r2 = Am[2*SA+k], r3 = Am[3*SA+k];
                const double c0 = An[0*SA+k]*dk, c1 = An[1*SA+k]*dk, c2 = An[2*SA+k]*dk, c3 = An[3*SA+k]*dk;
                a00 += r0*c0; a01 += r0*c1; a02 += r0*c2; a03 += r0*c3;
                a10 += r1*c0; a11 += r1*c1; a12 += r1*c2; a13 += r1*c3;
                a20 += r2*c0; a21 += r2*c1; a22 += r2*c2; a23 += r2*c3;
                a30 += r3*c0; a31 += r3*c1; a32 += r3*c2; a33 += r3*c3;
            }
            double* Sp = &Sl[(4 * mb) * SS + 4 * nb];
            Sp[0*SS+0]=a00; Sp[0*SS+1]=a01; Sp[0*SS+2]=a02; Sp[0*SS+3]=a03;
            Sp[1*SS+0]=a10; Sp[1*SS+1]=a11; Sp[1*SS+2]=a12; Sp[1*SS+3]=a13;
            Sp[2*SS+0]=a20; Sp[2*SS+1]=a21; Sp[2*SS+2]=a22; Sp[2*SS+3]=a23;
            Sp[3*SS+0]=a30; Sp[3*SS+1]=a31; Sp[3*SS+2]=a32; Sp[3*SS+3]=a33;
        }
        __syncthreads();   // barrier 1: tiles visible

        // ---- load row tid of S into registers (symmetric fill) ----
        double Sreg[MEQ];
        double diag_r;
        if (tid < MEQ) {
            #pragma unroll
            for (int j = 0; j < MEQ; ++j)
                Sreg[j] = (j <= tid) ? Sl[tid * SS + j] : Sl[j * SS + tid];
            diag_r = Sl[tid * SS + tid];
        } else {
            #pragma unroll
            for (int j = 0; j < MEQ; ++j) Sreg[j] = 0.0;
            diag_r = -1.0e308;
        }
        double dg = diag_r;
        for (int off = 32; off; off >>= 1) dg = fmax(dg, __shfl_xor(dg, off, 64));
        const double thr = dg * PIV_DROP_REL;
        __syncthreads();   // barrier 2: Sl free for next iteration

        // ---- P3: greedy-max-pivot LDL^T + fused forward solve (registers) ----
        double Lmh[MEQ];
        double ip_own = 0.0;
        int    kk_own = 0;
        #pragma unroll
        for (int t = 0; t < MEQ; ++t) {
            // argmax over remaining diagonal (selector butterfly, uniform flow)
            double v = diag_r; int idx = tid;
            for (int off = 32; off; off >>= 1) {
                const double ov = __shfl_xor(v, off, 64);
                const int    oi = __shfl_xor(idx, off, 64);
                if (ov > v || (ov == v && oi < idx)) { v = ov; idx = oi; }
            }
            const int kt = __builtin_amdgcn_readfirstlane(idx);
            // col_i = S[i][kt] — uniform select chain over static registers
            double col = Sreg[0];
            #pragma unroll
            for (int j = 1; j < MEQ; ++j) if (j == kt) col = Sreg[j];
            // pivot from the stored copy (lane kt's diagonal)
            const double piv  = __shfl(col, kt, 64);
            const double invP = (piv > thr) ? (1.0 / piv) : 0.0;  // drop noise pivots
            if (tid == t) { kk_own = kt; ip_own = invP; }
            const double Lm = (diag_r > -1.0e307 && tid != kt) ? col * invP : 0.0;
            Lmh[t] = Lm;
            const double fyk = __shfl(fy_r, kt, 64);
            fy_r -= Lm * fyk;                       // unit-L forward solve
            #pragma unroll
            for (int j = 0; j < MEQ; ++j) {         // rank-1 trailing update
                const double urj = __shfl(Sreg[j], kt, 64);   // pivot row (stored)
                Sreg[j] -= Lm * urj;
            }
            diag_r -= Lm * col;                     // selector maintenance
            if (tid == kt) diag_r = -1.0e308;       // eliminated
        }

        // ---- P4: backward solve x_t = w_t*invP_t - sum_i Lmh[t]_i * X_i ----
        double X_r = 0.0;                           // dy at owner lanes
        #pragma unroll
        for (int t = MEQ - 1; t >= 0; --t) {
            double ssum = Lmh[t] * X_r;
            for (int off = 32; off; off >>= 1) ssum += __shfl_xor(ssum, off, 64);
            const int    kt  = __shfl(kk_own, t, 64);
            const double ipt = __shfl(ip_own, t, 64);
            const double fyk = __shfl(fy_r, kt, 64);
            double xt = fyk * ipt - ssum;
            xt = (ipt != 0.0) ? xt : 0.0;           // dropped direction -> 0
            if (tid == kt) X_r = xt;
        }

        // ---- P5: dx/ds/dz, ratio test, updates (uniform flow) ----
        double atdy = 0.0;
        #pragma unroll 4
        for (int j = 0; j < MEQ; ++j) atdy += Ald[j * SA + tid] * __shfl(X_r, j, 64);
        const double dx = d_r * (rx - atdy);
        const double ds = dx - rs;                   // -rs + dx
        const double dz = rc - (z_r / s_r) * dx;
        double r = 1.0e300;
        if (ds < 0.0) r = -s_r / ds;
        if (dz < 0.0) r = fmin(r, -z_r / dz);
        for (int off = 32; off; off >>= 1) r = fmin(r, __shfl_xor(r, off, 64));
        const double alpha = fmin(1.0, FTB_C * r);
        x_r += alpha * dx;
        s_r += alpha * ds;
        z_r += alpha * dz;
        y_r += alpha * X_r;                          // X_r==0 for lanes>=40
    }

    out[b * NXV + tid] = (float)x_r;
}

extern "C" void kernel_launch(void* const* d_in, const int* in_sizes, int n_in,
                              void* d_out, int out_size, void* d_ws, size_t ws_size,
                              hipStream_t stream) {
    const float* puzzles = (const float*)d_in[0];
    const float* A       = (const float*)d_in[1];   // declared f64, delivered f32
    const float* logz0   = (const float*)d_in[2];
    // d_in[3] = Q (zeros, structural), d_in[4] = G (-I, structural)
    const float* u       = (const float*)d_in[5];
    float* out = (float*)d_out;

    const int n_batch = in_sizes[0] / NXV;   // 1024
    qp_ipm_kernel<<<n_batch, 64, 0, stream>>>(puzzles, A, logz0, u, out);
}